// Round 5
// baseline (274.695 us; speedup 1.0000x reference)
//
#include <hip/hip_runtime.h>
#include <hip/hip_bf16.h>
#include <stdint.h>

typedef __attribute__((ext_vector_type(8))) short s16x8;
typedef __attribute__((ext_vector_type(4))) float f32x4;

#define THRESH 0.3f
#define Mdim 8192
#define Kdim 2048
#define Ndim 8192
#define NT 32   // K-tiles of 64
#define NIT 16  // 2 K-tiles per iteration

static __device__ __forceinline__ unsigned short f2bf(float f) {
  __hip_bfloat16 h = __float2bfloat16(f);
  return __builtin_bit_cast(unsigned short, h);
}

// ---- Pass 1a: x fp32 -> bf16 (vectorized) ----
__global__ void cvt_x_kernel(const float* __restrict__ x,
                             unsigned short* __restrict__ xb, long n4) {
  long i = (long)blockIdx.x * blockDim.x + threadIdx.x;
  long stride = (long)gridDim.x * blockDim.x;
  for (; i < n4; i += stride) {
    float4 v = reinterpret_cast<const float4*>(x)[i];
    ushort4 o;
    o.x = f2bf(v.x); o.y = f2bf(v.y); o.z = f2bf(v.z); o.w = f2bf(v.w);
    reinterpret_cast<ushort4*>(xb)[i] = o;
  }
}

// ---- Pass 1b: w [K][N] fp32 -> ternary bf16 transposed [N][K] ----
__global__ void tern_tr_kernel(const float* __restrict__ w,
                               unsigned short* __restrict__ bt) {
  __shared__ unsigned short tile[32][33];
  int n0 = blockIdx.x * 32, k0 = blockIdx.y * 32;
  int tx = threadIdx.x, ty = threadIdx.y;  // (32, 8)
  #pragma unroll
  for (int j = 0; j < 4; ++j) {
    int k = k0 + ty + j * 8;
    float v = w[(long)k * Ndim + n0 + tx];
    unsigned short t = (fabsf(v) > THRESH) ? (v > 0.f ? 0x3F80u : 0xBF80u) : 0u;
    tile[ty + j * 8][tx] = t;
  }
  __syncthreads();
  #pragma unroll
  for (int j = 0; j < 4; ++j) {
    int n = n0 + ty + j * 8;
    bt[(long)n * Kdim + k0 + tx] = tile[tx][ty + j * 8];
  }
}

// ---- Pass 2: 256x256 8-phase bf16 MFMA GEMM, C = A * Bt^T ----
// 8 waves (2M x 4N), BK=64, XOR-swizzled reads, pre-swizzled global sources,
// counted vmcnt, setprio. Round-5 change: A TRIPLE-buffered (prefetch depth
// t+2, flight >= 6 phases ~2000cy > 900cy HBM latency) so the q3 vmcnt gate
// is never exposed. LDS = 3*32K (A) + 2*32K (B) = 160 KiB (gfx950 max).
__global__ void __launch_bounds__(512, 1) gemm8_kernel(
    const unsigned short* __restrict__ A,   // [8192][2048] bf16
    const unsigned short* __restrict__ Bt,  // [8192][2048] bf16 (N-major)
    float* __restrict__ C) {                // [8192][8192] fp32
  // layout: Abuf[j] at j*32768 (j=0..2); Bbuf[j] at 98304 + j*32768 (j=0..1)
  __shared__ __align__(128) char lds[163840];

  int bid = blockIdx.x;
  // 2D XCD-chunked swizzle (bijective over 32x32 tiles): XCD x owns tm-band
  // [4x,4x+4); within, 4(tm) x 8(tn) chunks -> concurrent set shares
  // 4 A-panels + 8 B-panels (cache-resident).
  int x = bid & 7;        // XCD
  int o = bid >> 3;       // 0..127 position within this XCD's sequence
  int c = o >> 5;         // time-chunk 0..3 (tn groups of 8)
  int w = o & 31;         // position within chunk
  int tm = x * 4 + (w >> 3);
  int tn = c * 8 + (w & 7);
  long arow0 = (long)tm * 256;
  long bcol0 = (long)tn * 256;

  int tid = threadIdx.x;
  int lane = tid & 63, wid = tid >> 6;
  int wr = wid >> 2, wc = wid & 3;  // 2M x 4N waves; per-wave C = 128x64
  int lr = lane & 15, lk = lane >> 4;

  // stage one half-tile (128 rows x 64 cols bf16 = 16KB) of tile u.
  // which: 0=A (buf u%3), 1=B (buf u&1). Linear LDS dest; INVERSE-swizzled
  // global source (both-sides-or-neither rule).
  auto stage = [&](int u, int which, int h) {
    if (u >= NT) return;
    const unsigned short* gsrc = which ? Bt : A;
    long grow0 = which ? bcol0 : arow0;
    int base = (which ? (98304 + (u & 1) * 32768) : ((u % 3) * 32768)) +
               h * 16384;
    int kt = u * 64;
    #pragma unroll
    for (int cc = 0; cc < 2; ++cc) {
      int s = cc * 512 + tid;         // 16B slot index 0..1023
      int r = h * 128 + (s >> 3);     // tile row
      int co = (s & 7) ^ (r & 7);     // original 16B chunk within the row
      const unsigned short* g = gsrc + (grow0 + r) * (long)Kdim + kt + co * 8;
      __builtin_amdgcn_global_load_lds(
          (const __attribute__((address_space(1))) void*)g,
          (__attribute__((address_space(3))) void*)(lds + base +
                                                   (cc * 512 + wid * 64) * 16),
          16, 0, 0);
    }
  };

  // swizzled fragment read: row-major [*][64] bf16 at byte base,
  // byte ^= (row&7)<<4
  auto frag = [&](int base, int row, int kcol) -> s16x8 {
    int off = base + row * 128 + (((kcol >> 3) ^ (row & 7)) << 4);
    return *reinterpret_cast<const s16x8*>(lds + off);
  };

  f32x4 acc[8][4] = {};
  s16x8 bf[4][2];

  // prologue: tiles 0 and 1 fully staged (16 loads); wait for tile 0's 8.
  stage(0, 0, 0); stage(0, 0, 1); stage(0, 1, 0); stage(0, 1, 1);
  stage(1, 0, 0); stage(1, 0, 1); stage(1, 1, 0); stage(1, 1, 1);
  asm volatile("s_waitcnt vmcnt(8)" ::: "memory");
  __builtin_amdgcn_s_barrier();

  for (int it = 0; it < NIT; ++it) {
    int t = 2 * it;
    #pragma unroll
    for (int half = 0; half < 2; ++half) {
      int cur = t + half;
      int abase = (cur % 3) * 32768;
      int bbase = 98304 + (cur & 1) * 32768;
      int u = cur + 2;  // both A and B stage target this tile
      #pragma unroll
      for (int q = 0; q < 4; ++q) {
        // ds-load register subtile for this phase
        s16x8 af[2][2];
        #pragma unroll
        for (int m = 0; m < 2; ++m)
          #pragma unroll
          for (int ks = 0; ks < 2; ++ks)
            af[m][ks] = frag(abase, wr * 128 + q * 32 + m * 16 + lr,
                             ks * 32 + lk * 8);
        if (q == 0) {
          #pragma unroll
          for (int n = 0; n < 4; ++n)
            #pragma unroll
            for (int ks = 0; ks < 2; ++ks)
              bf[n][ks] = frag(bbase, wc * 64 + n * 16 + lr, ks * 32 + lk * 8);
        }
        // stage one half-tile prefetch of tile cur+2
        if (q == 0) stage(u, 0, 0);
        else if (q == 1) stage(u, 0, 1);
        else if (q == 2) stage(u, 1, 0);
        else stage(u, 1, 1);

        if (q == 0) asm volatile("s_waitcnt lgkmcnt(8)" ::: "memory");
        __builtin_amdgcn_s_barrier();
        asm volatile("s_waitcnt lgkmcnt(0)" ::: "memory");
        __builtin_amdgcn_s_setprio(1);
        #pragma unroll
        for (int ks = 0; ks < 2; ++ks)
          #pragma unroll
          for (int m = 0; m < 2; ++m)
            #pragma unroll
            for (int n = 0; n < 4; ++n)
              acc[q * 2 + m][n] = __builtin_amdgcn_mfma_f32_16x16x32_bf16(
                  af[m][ks], bf[n][ks], acc[q * 2 + m][n], 0, 0, 0);
        __builtin_amdgcn_s_setprio(0);
        if (q == 3) {
          // gate: exempt exactly this tile's 8 in-flight loads; everything
          // older (incl. tile cur+1's A and B) must have landed. When the
          // stages were skipped (u >= NT), drain fully so tile cur+1's
          // loads (issued during cur-1) are guaranteed.
          if (u < NT) asm volatile("s_waitcnt vmcnt(8)" ::: "memory");
          else        asm volatile("s_waitcnt vmcnt(0)" ::: "memory");
        }
        __builtin_amdgcn_s_barrier();
      }
    }
  }

  // epilogue: D row = lk*4 + reg, col = lr within each 16x16 fragment
  #pragma unroll
  for (int m = 0; m < 8; ++m) {
    long row0 = arow0 + wr * 128 + m * 16 + lk * 4;
    #pragma unroll
    for (int n = 0; n < 4; ++n) {
      long col = bcol0 + wc * 64 + n * 16 + lr;
      #pragma unroll
      for (int r = 0; r < 4; ++r)
        C[(row0 + r) * Ndim + col] = acc[m][n][r];
    }
  }
}

// ---- fallback if d_ws is too small: simple tiled fp32 GEMM ----
__global__ void fallback_gemm(const float* __restrict__ x,
                              const float* __restrict__ w,
                              float* __restrict__ C) {
  __shared__ float As[16][17];
  __shared__ float Bs[16][17];
  int tx = threadIdx.x, ty = threadIdx.y;
  long row = (long)blockIdx.y * 16 + ty;
  long col = (long)blockIdx.x * 16 + tx;
  float s = 0.f;
  for (int k0 = 0; k0 < Kdim; k0 += 16) {
    As[ty][tx] = x[row * Kdim + k0 + tx];
    float v = w[(long)(k0 + ty) * Ndim + col];
    Bs[ty][tx] = (fabsf(v) > THRESH) ? (v > 0.f ? 1.f : -1.f) : 0.f;
    __syncthreads();
    #pragma unroll
    for (int k = 0; k < 16; ++k) s += As[ty][k] * Bs[k][tx];
    __syncthreads();
  }
  C[row * Ndim + col] = s;
}

extern "C" void kernel_launch(void* const* d_in, const int* in_sizes, int n_in,
                              void* d_out, int out_size, void* d_ws, size_t ws_size,
                              hipStream_t stream) {
  const float* x = (const float*)d_in[0];
  const float* w = (const float*)d_in[1];
  float* out = (float*)d_out;

  size_t abytes = (size_t)Mdim * Kdim * 2;  // 32 MB
  size_t bbytes = (size_t)Ndim * Kdim * 2;  // 32 MB

  if (ws_size >= abytes + bbytes) {
    unsigned short* xb = (unsigned short*)d_ws;
    unsigned short* bt = (unsigned short*)((char*)d_ws + abytes);
    cvt_x_kernel<<<4096, 256, 0, stream>>>(x, xb, (long)Mdim * Kdim / 4);
    tern_tr_kernel<<<dim3(Ndim / 32, Kdim / 32), dim3(32, 8), 0, stream>>>(w, bt);
    gemm8_kernel<<<1024, 512, 0, stream>>>(xb, bt, out);
  } else {
    fallback_gemm<<<dim3(Ndim / 16, Mdim / 16), dim3(16, 16), 0, stream>>>(x, w, out);
  }
}